// Round 1
// baseline (1297.370 us; speedup 1.0000x reference)
//
#include <hip/hip_runtime.h>
#include <math.h>
#include <float.h>

#define NN 50000
#define EE 800000
#define FF 64
#define EDIM 16
#define GG 64

// ---------------------------------------------------------------- degree
__global__ void k_deg(const int* __restrict__ eidx, int* __restrict__ deg) {
  int e = blockIdx.x * 256 + threadIdx.x;
  if (e < EE) atomicAdd(&deg[eidx[EE + e]], 1);
}

// ---------------------------------------------------------------- avg log(deg+1)
__global__ void k_avglog(const int* __restrict__ deg, double* __restrict__ acc) {
  int n = blockIdx.x * 256 + threadIdx.x;
  float v = (n < NN) ? logf((float)deg[n] + 1.0f) : 0.0f;
  __shared__ float s[256];
  s[threadIdx.x] = v;
  __syncthreads();
  for (int o = 128; o > 0; o >>= 1) {
    if (threadIdx.x < o) s[threadIdx.x] += s[threadIdx.x + o];
    __syncthreads();
  }
  if (threadIdx.x == 0) atomicAdd(acc, (double)s[0]);
}

// ---------------------------------------------------------------- exclusive scan of deg -> offsets (single block)
__global__ __launch_bounds__(1024) void k_scan(const int* __restrict__ deg, int* __restrict__ offsets) {
  __shared__ int wsum[16];
  __shared__ int s_carry;
  int t = threadIdx.x;
  int lane = t & 63;
  int wid = t >> 6;
  if (t == 0) s_carry = 0;
  __syncthreads();
  for (int base = 0; base < NN; base += 1024) {
    int idx = base + t;
    int v = (idx < NN) ? deg[idx] : 0;
    int x = v;
    #pragma unroll
    for (int o = 1; o < 64; o <<= 1) {
      int y = __shfl_up(x, o);
      if (lane >= o) x += y;
    }
    if (lane == 63) wsum[wid] = x;
    __syncthreads();
    if (wid == 0 && lane < 16) {
      int wv = wsum[lane];
      #pragma unroll
      for (int o = 1; o < 16; o <<= 1) {
        int y = __shfl_up(wv, o);
        if (lane >= o) wv += y;
      }
      wsum[lane] = wv;
    }
    __syncthreads();
    int pre = (wid > 0 ? wsum[wid - 1] : 0) + s_carry;
    if (idx < NN) offsets[idx] = pre + x - v;  // exclusive
    __syncthreads();
    if (t == 0) s_carry += wsum[15];
    __syncthreads();
  }
  if (threadIdx.x == 0) offsets[NN] = s_carry;
}

// ---------------------------------------------------------------- scatter edges into CSR slots
__global__ void k_scatter(const int* __restrict__ eidx, const int* __restrict__ offsets,
                          int* __restrict__ cursor, int2* __restrict__ pack) {
  int e = blockIdx.x * 256 + threadIdx.x;
  if (e < EE) {
    int s = eidx[e];
    int d = eidx[EE + e];
    int pos = offsets[d] + atomicAdd(&cursor[d], 1);
    pack[pos] = make_int2(s, e);
  }
}

// ---------------------------------------------------------------- amp/att
__global__ void k_ampatt(const int* __restrict__ deg, const double* __restrict__ acc,
                         float* __restrict__ amp, float* __restrict__ att) {
  int n = blockIdx.x * 256 + threadIdx.x;
  if (n < NN) {
    float avg = (float)(acc[0] / (double)NN);
    float d = (float)deg[n];
    float logd = logf(fmaxf(d, 1.0f) + 1.0f);
    amp[n] = logd / avg;
    att[n] = avg / logd;
  }
}

// ---------------------------------------------------------------- per-layer prep: Mw = We@WpreE, bconst = bpre + be@WpreE; zero BN accs
__global__ void k_prep(const float* __restrict__ We, const float* __restrict__ be,
                       const float* __restrict__ Wpre, const float* __restrict__ bpre,
                       float* __restrict__ Mw, float* __restrict__ bconst,
                       double* __restrict__ bnsum, double* __restrict__ bnsq) {
  int f = threadIdx.x;  // 0..63
  for (int k = 0; k < EDIM; k++) {
    float a = 0.0f;
    for (int j = 0; j < FF; j++) a += We[k * FF + j] * Wpre[(128 + j) * FF + f];
    Mw[k * FF + f] = a;
  }
  float b = bpre[f];
  for (int j = 0; j < FF; j++) b += be[j] * Wpre[(128 + j) * FF + f];
  bconst[f] = b;
  bnsum[f] = 0.0;
  bnsq[f] = 0.0;
}

// ---------------------------------------------------------------- Xd = x@Wpre[0:64], Xs = x@Wpre[64:128]
__global__ __launch_bounds__(256) void k_xform(const float* __restrict__ x, const float* __restrict__ Wpre,
                                               float* __restrict__ Xd, float* __restrict__ Xs) {
  __shared__ float xt[64 * 64];
  int t = threadIdx.x;
  int n0 = blockIdx.x * 64;
  {
    int r = t >> 2;
    int c0 = (t & 3) * 4;
    bool ok = (n0 + r) < NN;
    const float4* src = (const float4*)(x + (size_t)(n0 + r) * FF);
    #pragma unroll
    for (int c4 = 0; c4 < 4; c4++) {
      int c = c0 + c4;
      float4 v = ok ? src[c] : make_float4(0.f, 0.f, 0.f, 0.f);
      int cs = c ^ (r & 15);
      *((float4*)&xt[r * 64 + cs * 4]) = v;
    }
  }
  __syncthreads();
  int lane = t & 63;
  int wid = __builtin_amdgcn_readfirstlane(t >> 6);
  int f0 = wid * 16;
  float accd[16], accs[16];
  #pragma unroll
  for (int j = 0; j < 16; j++) { accd[j] = 0.f; accs[j] = 0.f; }
  for (int kk = 0; kk < 16; kk++) {
    int cs = kk ^ (lane & 15);
    float4 a4 = *((const float4*)&xt[lane * 64 + cs * 4]);
    const float* ap = (const float*)&a4;
    #pragma unroll
    for (int j4 = 0; j4 < 4; j4++) {
      int k = kk * 4 + j4;
      float av = ap[j4];
      #pragma unroll
      for (int j = 0; j < 16; j++) {
        accd[j] += av * Wpre[k * FF + f0 + j];
        accs[j] += av * Wpre[(64 + k) * FF + f0 + j];
      }
    }
  }
  int n = n0 + lane;
  if (n < NN) {
    #pragma unroll
    for (int c4 = 0; c4 < 4; c4++) {
      float4 vd = make_float4(accd[c4 * 4 + 0], accd[c4 * 4 + 1], accd[c4 * 4 + 2], accd[c4 * 4 + 3]);
      float4 vs = make_float4(accs[c4 * 4 + 0], accs[c4 * 4 + 1], accs[c4 * 4 + 2], accs[c4 * 4 + 3]);
      *(float4*)(Xd + (size_t)n * FF + f0 + c4 * 4) = vd;
      *(float4*)(Xs + (size_t)n * FF + f0 + c4 * 4) = vs;
    }
  }
}

// ---------------------------------------------------------------- per-node CSR aggregation -> aggs [N,256] = [mean,mn,mx,std]
__global__ __launch_bounds__(256) void k_agg(const int2* __restrict__ pack, const int* __restrict__ offsets,
                                             const int* __restrict__ deg, const float* __restrict__ eattr,
                                             const float* __restrict__ Mw, const float* __restrict__ bconst,
                                             const float* __restrict__ Xd, const float* __restrict__ Xs,
                                             float* __restrict__ aggs) {
  int wid = __builtin_amdgcn_readfirstlane(threadIdx.x >> 6);
  int lane = threadIdx.x & 63;
  int n = blockIdx.x * 4 + wid;
  if (n >= NN) return;
  float mw[16];
  #pragma unroll
  for (int k = 0; k < 16; k++) mw[k] = Mw[k * FF + lane];
  float bc = bconst[lane];
  float xd = Xd[(size_t)n * FF + lane];
  int o0 = offsets[n], o1 = offsets[n + 1];
  float s = 0.f, sq = 0.f, mn = FLT_MAX, mx = -FLT_MAX;
  for (int i = o0; i < o1; i++) {
    int2 p = pack[i];
    int src = p.x, eid = p.y;
    const float4* eap = (const float4*)(eattr + (size_t)eid * EDIM);
    float4 e0 = eap[0], e1 = eap[1], e2 = eap[2], e3 = eap[3];
    float xs = Xs[(size_t)src * FF + lane];
    float et = e0.x * mw[0] + e0.y * mw[1] + e0.z * mw[2] + e0.w * mw[3]
             + e1.x * mw[4] + e1.y * mw[5] + e1.z * mw[6] + e1.w * mw[7]
             + e2.x * mw[8] + e2.y * mw[9] + e2.z * mw[10] + e2.w * mw[11]
             + e3.x * mw[12] + e3.y * mw[13] + e3.z * mw[14] + e3.w * mw[15];
    float h = xd + xs + bc + et;
    s += h;
    sq += h * h;
    mn = fminf(mn, h);
    mx = fmaxf(mx, h);
  }
  float d = (float)deg[n];
  float dc = fmaxf(d, 1.0f);
  float mean = s / dc;
  float msq = sq / dc;
  float sd = sqrtf(fmaxf(msq - mean * mean, 0.0f) + 1e-5f);
  bool has = d > 0.0f;
  float vmn = has ? mn : 0.0f;
  float vmx = has ? mx : 0.0f;
  size_t b = (size_t)n * 256;
  aggs[b + lane] = mean;
  aggs[b + 64 + lane] = vmn;
  aggs[b + 128 + lane] = vmx;
  aggs[b + 192 + lane] = sd;
}

// ---------------------------------------------------------------- y = (A @ Wpost + bpost) @ Wlin + blin,  A = [x, aggs, amp*aggs, att*aggs]
__global__ __launch_bounds__(256) void k_post(const float* __restrict__ x, const float* __restrict__ aggs,
                                              const float* __restrict__ amp, const float* __restrict__ att,
                                              const float* __restrict__ Wpost, const float* __restrict__ bpost,
                                              const float* __restrict__ Wlin, const float* __restrict__ blin,
                                              float* __restrict__ y) {
  __shared__ float At[64 * 64];
  __shared__ float Ot[64 * 64];
  int t = threadIdx.x;
  int lane = t & 63;
  int wid = __builtin_amdgcn_readfirstlane(t >> 6);
  int f0 = wid * 16;
  int n0 = blockIdx.x * 64;
  int row = t >> 2;
  int c0 = (t & 3) * 4;
  bool rok = (n0 + row) < NN;
  float sc_amp = rok ? amp[n0 + row] : 0.f;
  float sc_att = rok ? att[n0 + row] : 0.f;
  float acc[16];
  #pragma unroll
  for (int j = 0; j < 16; j++) acc[j] = 0.f;

  for (int kc = 0; kc < 13; kc++) {
    // stage A[64][kc*64 .. kc*64+63] (each 64-chunk lies in one region)
    const float* srcb;
    float scale = 1.0f;
    if (kc == 0) {
      srcb = x + (size_t)(n0 + row) * FF;
    } else if (kc <= 4) {
      srcb = aggs + (size_t)(n0 + row) * 256 + (kc - 1) * 64;
    } else if (kc <= 8) {
      srcb = aggs + (size_t)(n0 + row) * 256 + (kc - 5) * 64;
      scale = sc_amp;
    } else {
      srcb = aggs + (size_t)(n0 + row) * 256 + (kc - 9) * 64;
      scale = sc_att;
    }
    #pragma unroll
    for (int c4 = 0; c4 < 4; c4++) {
      int c = c0 + c4;
      float4 v = rok ? *(const float4*)(srcb + c * 4) : make_float4(0.f, 0.f, 0.f, 0.f);
      v.x *= scale; v.y *= scale; v.z *= scale; v.w *= scale;
      int cs = c ^ (row & 15);
      *(float4*)&At[row * 64 + cs * 4] = v;
    }
    __syncthreads();
    int kbase = kc * 64;
    for (int kk = 0; kk < 16; kk++) {
      int cs2 = kk ^ (lane & 15);
      float4 a4 = *(const float4*)&At[lane * 64 + cs2 * 4];
      const float* ap = (const float*)&a4;
      #pragma unroll
      for (int j4 = 0; j4 < 4; j4++) {
        int k = kbase + kk * 4 + j4;
        float av = ap[j4];
        #pragma unroll
        for (int j = 0; j < 16; j++) acc[j] += av * Wpost[(size_t)k * FF + f0 + j];
      }
    }
    __syncthreads();
  }
  // out1 = acc + bpost -> stage to Ot
  #pragma unroll
  for (int j = 0; j < 16; j++) acc[j] += bpost[f0 + j];
  #pragma unroll
  for (int c4 = 0; c4 < 4; c4++) {
    int c = wid * 4 + c4;
    int cs = c ^ (lane & 15);
    float4 v = make_float4(acc[c4 * 4 + 0], acc[c4 * 4 + 1], acc[c4 * 4 + 2], acc[c4 * 4 + 3]);
    *(float4*)&Ot[lane * 64 + cs * 4] = v;
  }
  __syncthreads();
  float acc2[16];
  #pragma unroll
  for (int j = 0; j < 16; j++) acc2[j] = blin[f0 + j];
  for (int kk = 0; kk < 16; kk++) {
    int cs2 = kk ^ (lane & 15);
    float4 a4 = *(const float4*)&Ot[lane * 64 + cs2 * 4];
    const float* ap = (const float*)&a4;
    #pragma unroll
    for (int j4 = 0; j4 < 4; j4++) {
      int k = kk * 4 + j4;
      float av = ap[j4];
      #pragma unroll
      for (int j = 0; j < 16; j++) acc2[j] += av * Wlin[k * FF + f0 + j];
    }
  }
  if (n0 + lane < NN) {
    #pragma unroll
    for (int c4 = 0; c4 < 4; c4++) {
      float4 v = make_float4(acc2[c4 * 4 + 0], acc2[c4 * 4 + 1], acc2[c4 * 4 + 2], acc2[c4 * 4 + 3]);
      *(float4*)(y + (size_t)(n0 + lane) * FF + f0 + c4 * 4) = v;
    }
  }
}

// ---------------------------------------------------------------- BN stats
__global__ __launch_bounds__(256) void k_bnstats(const float* __restrict__ y, double* __restrict__ bnsum,
                                                 double* __restrict__ bnsq) {
  int f = threadIdx.x & 63;
  int rw = threadIdx.x >> 6;
  float s = 0.f, q = 0.f;
  for (int n = blockIdx.x * 4 + rw; n < NN; n += gridDim.x * 4) {
    float v = y[(size_t)n * FF + f];
    s += v;
    q += v * v;
  }
  __shared__ float ls[256], lq[256];
  ls[threadIdx.x] = s;
  lq[threadIdx.x] = q;
  __syncthreads();
  if (threadIdx.x < 64) {
    s = ls[f] + ls[f + 64] + ls[f + 128] + ls[f + 192];
    q = lq[f] + lq[f + 64] + lq[f + 128] + lq[f + 192];
    atomicAdd(&bnsum[f], (double)s);
    atomicAdd(&bnsq[f], (double)q);
  }
}

// ---------------------------------------------------------------- BN apply (+relu); last layer also pools
__global__ __launch_bounds__(256) void k_bnapply(const float* __restrict__ y, const double* __restrict__ bnsum,
                                                 const double* __restrict__ bnsq, const float* __restrict__ gamma,
                                                 const float* __restrict__ beta, float* __restrict__ xout,
                                                 const int* __restrict__ batch, float* __restrict__ psum,
                                                 float* __restrict__ cnt, int last) {
  int f = threadIdx.x & 63;
  int rw = threadIdx.x >> 6;
  double mu_d = bnsum[f] / (double)NN;
  double var_d = bnsq[f] / (double)NN - mu_d * mu_d;
  float mu = (float)mu_d;
  float sc = gamma[f] * rsqrtf((float)fmax(var_d, 0.0) + 1e-5f);
  float bi = beta[f];
  for (int n = blockIdx.x * 4 + rw; n < NN; n += gridDim.x * 4) {
    float v = fmaxf((y[(size_t)n * FF + f] - mu) * sc + bi, 0.0f);
    if (!last) {
      xout[(size_t)n * FF + f] = v;
    } else {
      int g = batch[n];
      atomicAdd(&psum[g * FF + f], v);
      if (f == 0) atomicAdd(&cnt[g], 1.0f);
    }
  }
}

// ---------------------------------------------------------------- final MLP over pooled means
__global__ void k_final(const float* __restrict__ psum, const float* __restrict__ cnt,
                        const float* __restrict__ W1, const float* __restrict__ b1,
                        const float* __restrict__ W2, const float* __restrict__ b2, float* __restrict__ out) {
  int g = threadIdx.x;
  if (g >= GG) return;
  float c = fmaxf(cnt[g], 1.0f);
  float gm[64];
  #pragma unroll
  for (int i = 0; i < 64; i++) gm[i] = psum[g * FF + i] / c;
  float o = b2[0];
  for (int h = 0; h < 40; h++) {
    float a = b1[h];
    #pragma unroll
    for (int i = 0; i < 64; i++) a += gm[i] * W1[i * 40 + h];
    o += fmaxf(a, 0.0f) * W2[h];
  }
  out[g] = o;
}

// ================================================================ launch
extern "C" void kernel_launch(void* const* d_in, const int* in_sizes, int n_in,
                              void* d_out, int out_size, void* d_ws, size_t ws_size,
                              hipStream_t stream) {
  (void)in_sizes; (void)n_in; (void)out_size; (void)ws_size;
  const float* x0    = (const float*)d_in[0];
  const float* eattr = (const float*)d_in[1];
  const float* We    = (const float*)d_in[2];
  const float* be    = (const float*)d_in[3];
  const float* Wpre  = (const float*)d_in[4];
  const float* bpre  = (const float*)d_in[5];
  const float* Wpost = (const float*)d_in[6];
  const float* bpost = (const float*)d_in[7];
  const float* Wlin  = (const float*)d_in[8];
  const float* blin  = (const float*)d_in[9];
  const float* gamma = (const float*)d_in[10];
  const float* beta  = (const float*)d_in[11];
  const float* W1    = (const float*)d_in[12];
  const float* b1    = (const float*)d_in[13];
  const float* W2    = (const float*)d_in[14];
  const float* b2    = (const float*)d_in[15];
  const int* eidx    = (const int*)d_in[16];
  const int* batch   = (const int*)d_in[17];
  float* out = (float*)d_out;

  char* w = (char*)d_ws;
  size_t off = 0;
  auto alloc = [&](size_t bytes) -> void* {
    void* p = w + off;
    off += bytes;
    off = (off + 255) & ~(size_t)255;
    return p;
  };
  int*    deg     = (int*)alloc(NN * sizeof(int));
  int*    offsets = (int*)alloc((NN + 1) * sizeof(int));
  int*    cursor  = (int*)alloc(NN * sizeof(int));
  int2*   pack    = (int2*)alloc(EE * sizeof(int2));
  double* avgacc  = (double*)alloc(sizeof(double));
  double* bnsum   = (double*)alloc(FF * sizeof(double));
  double* bnsq    = (double*)alloc(FF * sizeof(double));
  float*  amp     = (float*)alloc(NN * sizeof(float));
  float*  att     = (float*)alloc(NN * sizeof(float));
  float*  Mw      = (float*)alloc(EDIM * FF * sizeof(float));
  float*  bconst  = (float*)alloc(FF * sizeof(float));
  float*  Xd      = (float*)alloc((size_t)NN * FF * sizeof(float));
  float*  Xs      = (float*)alloc((size_t)NN * FF * sizeof(float));
  float*  aggs    = (float*)alloc((size_t)NN * 256 * sizeof(float));
  float*  ybuf    = (float*)alloc((size_t)NN * FF * sizeof(float));
  float*  xcur    = (float*)alloc((size_t)NN * FF * sizeof(float));
  float*  psum    = (float*)alloc((GG * FF + GG) * sizeof(float));
  float*  cnt     = psum + GG * FF;

  hipMemsetAsync(deg, 0, NN * sizeof(int), stream);
  hipMemsetAsync(cursor, 0, NN * sizeof(int), stream);
  hipMemsetAsync(avgacc, 0, sizeof(double), stream);
  hipMemsetAsync(psum, 0, (GG * FF + GG) * sizeof(float), stream);

  k_deg<<<(EE + 255) / 256, 256, 0, stream>>>(eidx, deg);
  k_avglog<<<(NN + 255) / 256, 256, 0, stream>>>(deg, avgacc);
  k_scan<<<1, 1024, 0, stream>>>(deg, offsets);
  k_scatter<<<(EE + 255) / 256, 256, 0, stream>>>(eidx, offsets, cursor, pack);
  k_ampatt<<<(NN + 255) / 256, 256, 0, stream>>>(deg, avgacc, amp, att);

  const float* xin = x0;
  const int nb64 = (NN + 63) / 64;  // 782
  for (int l = 0; l < 2; l++) {
    k_prep<<<1, 64, 0, stream>>>(We + l * EDIM * FF, be + l * FF, Wpre + l * 3 * FF * FF,
                                 bpre + l * FF, Mw, bconst, bnsum, bnsq);
    k_xform<<<nb64, 256, 0, stream>>>(xin, Wpre + l * 3 * FF * FF, Xd, Xs);
    k_agg<<<(NN + 3) / 4, 256, 0, stream>>>(pack, offsets, deg, eattr, Mw, bconst, Xd, Xs, aggs);
    k_post<<<nb64, 256, 0, stream>>>(xin, aggs, amp, att, Wpost + (size_t)l * 832 * FF,
                                     bpost + l * FF, Wlin + l * FF * FF, blin + l * FF, ybuf);
    k_bnstats<<<256, 256, 0, stream>>>(ybuf, bnsum, bnsq);
    k_bnapply<<<256, 256, 0, stream>>>(ybuf, bnsum, bnsq, gamma + l * FF, beta + l * FF,
                                       xcur, batch, psum, cnt, l == 1 ? 1 : 0);
    xin = xcur;
  }
  k_final<<<1, 64, 0, stream>>>(psum, cnt, W1, b1, W2, b2, out);
}

// Round 2
// 889.151 us; speedup vs baseline: 1.4591x; 1.4591x over previous
//
#include <hip/hip_runtime.h>
#include <math.h>
#include <float.h>

#define NN 50000
#define EE 800000
#define FF 64
#define EDIM 16
#define GG 64

// ---------------------------------------------------------------- degree
__global__ void k_deg(const int* __restrict__ eidx, int* __restrict__ deg) {
  int e = blockIdx.x * 256 + threadIdx.x;
  if (e < EE) atomicAdd(&deg[eidx[EE + e]], 1);
}

// ---------------------------------------------------------------- avg log(deg+1)
__global__ void k_avglog(const int* __restrict__ deg, double* __restrict__ acc) {
  int n = blockIdx.x * 256 + threadIdx.x;
  float v = (n < NN) ? logf((float)deg[n] + 1.0f) : 0.0f;
  __shared__ float s[256];
  s[threadIdx.x] = v;
  __syncthreads();
  for (int o = 128; o > 0; o >>= 1) {
    if (threadIdx.x < o) s[threadIdx.x] += s[threadIdx.x + o];
    __syncthreads();
  }
  if (threadIdx.x == 0) atomicAdd(acc, (double)s[0]);
}

// ---------------------------------------------------------------- exclusive scan of deg -> offsets (single block)
__global__ __launch_bounds__(1024) void k_scan(const int* __restrict__ deg, int* __restrict__ offsets) {
  __shared__ int wsum[16];
  __shared__ int s_carry;
  int t = threadIdx.x;
  int lane = t & 63;
  int wid = t >> 6;
  if (t == 0) s_carry = 0;
  __syncthreads();
  for (int base = 0; base < NN; base += 1024) {
    int idx = base + t;
    int v = (idx < NN) ? deg[idx] : 0;
    int x = v;
    #pragma unroll
    for (int o = 1; o < 64; o <<= 1) {
      int y = __shfl_up(x, o);
      if (lane >= o) x += y;
    }
    if (lane == 63) wsum[wid] = x;
    __syncthreads();
    if (wid == 0 && lane < 16) {
      int wv = wsum[lane];
      #pragma unroll
      for (int o = 1; o < 16; o <<= 1) {
        int y = __shfl_up(wv, o);
        if (lane >= o) wv += y;
      }
      wsum[lane] = wv;
    }
    __syncthreads();
    int pre = (wid > 0 ? wsum[wid - 1] : 0) + s_carry;
    if (idx < NN) offsets[idx] = pre + x - v;  // exclusive
    __syncthreads();
    if (t == 0) s_carry += wsum[15];
    __syncthreads();
  }
  if (threadIdx.x == 0) offsets[NN] = s_carry;
}

// ---------------------------------------------------------------- scatter edges into CSR slots
__global__ void k_scatter(const int* __restrict__ eidx, const int* __restrict__ offsets,
                          int* __restrict__ cursor, int2* __restrict__ pack) {
  int e = blockIdx.x * 256 + threadIdx.x;
  if (e < EE) {
    int s = eidx[e];
    int d = eidx[EE + e];
    int pos = offsets[d] + atomicAdd(&cursor[d], 1);
    pack[pos] = make_int2(s, e);
  }
}

// ---------------------------------------------------------------- amp/att
__global__ void k_ampatt(const int* __restrict__ deg, const double* __restrict__ acc,
                         float* __restrict__ amp, float* __restrict__ att) {
  int n = blockIdx.x * 256 + threadIdx.x;
  if (n < NN) {
    float avg = (float)(acc[0] / (double)NN);
    float d = (float)deg[n];
    float logd = logf(fmaxf(d, 1.0f) + 1.0f);
    amp[n] = logd / avg;
    att[n] = avg / logd;
  }
}

// ---------------------------------------------------------------- per-layer prep: Mw = We@WpreE, bconst = bpre + be@WpreE; zero BN accs
__global__ void k_prep(const float* __restrict__ We, const float* __restrict__ be,
                       const float* __restrict__ Wpre, const float* __restrict__ bpre,
                       float* __restrict__ Mw, float* __restrict__ bconst,
                       double* __restrict__ bnsum, double* __restrict__ bnsq) {
  int f = threadIdx.x;  // 0..63
  for (int k = 0; k < EDIM; k++) {
    float a = 0.0f;
    for (int j = 0; j < FF; j++) a += We[k * FF + j] * Wpre[(128 + j) * FF + f];
    Mw[k * FF + f] = a;
  }
  float b = bpre[f];
  for (int j = 0; j < FF; j++) b += be[j] * Wpre[(128 + j) * FF + f];
  bconst[f] = b;
  bnsum[f] = 0.0;
  bnsq[f] = 0.0;
}

// ---------------------------------------------------------------- Xd = x@Wpre[0:64], Xs = x@Wpre[64:128]
__global__ __launch_bounds__(256) void k_xform(const float* __restrict__ x, const float* __restrict__ Wpre,
                                               float* __restrict__ Xd, float* __restrict__ Xs) {
  __shared__ float xt[64 * 64];
  int t = threadIdx.x;
  int n0 = blockIdx.x * 64;
  {
    int r = t >> 2;
    int c0 = (t & 3) * 4;
    bool ok = (n0 + r) < NN;
    const float4* src = (const float4*)(x + (size_t)(n0 + r) * FF);
    #pragma unroll
    for (int c4 = 0; c4 < 4; c4++) {
      int c = c0 + c4;
      float4 v = ok ? src[c] : make_float4(0.f, 0.f, 0.f, 0.f);
      int cs = c ^ (r & 15);
      *((float4*)&xt[r * 64 + cs * 4]) = v;
    }
  }
  __syncthreads();
  int lane = t & 63;
  int wid = __builtin_amdgcn_readfirstlane(t >> 6);
  int f0 = wid * 16;
  float accd[16], accs[16];
  #pragma unroll
  for (int j = 0; j < 16; j++) { accd[j] = 0.f; accs[j] = 0.f; }
  for (int kk = 0; kk < 16; kk++) {
    int cs = kk ^ (lane & 15);
    float4 a4 = *((const float4*)&xt[lane * 64 + cs * 4]);
    const float* ap = (const float*)&a4;
    #pragma unroll
    for (int j4 = 0; j4 < 4; j4++) {
      int k = kk * 4 + j4;
      float av = ap[j4];
      #pragma unroll
      for (int j = 0; j < 16; j++) {
        accd[j] += av * Wpre[k * FF + f0 + j];
        accs[j] += av * Wpre[(64 + k) * FF + f0 + j];
      }
    }
  }
  int n = n0 + lane;
  if (n < NN) {
    #pragma unroll
    for (int c4 = 0; c4 < 4; c4++) {
      float4 vd = make_float4(accd[c4 * 4 + 0], accd[c4 * 4 + 1], accd[c4 * 4 + 2], accd[c4 * 4 + 3]);
      float4 vs = make_float4(accs[c4 * 4 + 0], accs[c4 * 4 + 1], accs[c4 * 4 + 2], accs[c4 * 4 + 3]);
      *(float4*)(Xd + (size_t)n * FF + f0 + c4 * 4) = vd;
      *(float4*)(Xs + (size_t)n * FF + f0 + c4 * 4) = vs;
    }
  }
}

// ---------------------------------------------------------------- per-node CSR aggregation -> aggs [N,256] = [mean,mn,mx,std]
__global__ __launch_bounds__(256) void k_agg(const int2* __restrict__ pack, const int* __restrict__ offsets,
                                             const int* __restrict__ deg, const float* __restrict__ eattr,
                                             const float* __restrict__ Mw, const float* __restrict__ bconst,
                                             const float* __restrict__ Xd, const float* __restrict__ Xs,
                                             float* __restrict__ aggs) {
  int wid = __builtin_amdgcn_readfirstlane(threadIdx.x >> 6);
  int lane = threadIdx.x & 63;
  int n = blockIdx.x * 4 + wid;
  if (n >= NN) return;
  float mw[16];
  #pragma unroll
  for (int k = 0; k < 16; k++) mw[k] = Mw[k * FF + lane];
  float bc = bconst[lane];
  float xd = Xd[(size_t)n * FF + lane];
  int o0 = offsets[n], o1 = offsets[n + 1];
  float s = 0.f, sq = 0.f, mn = FLT_MAX, mx = -FLT_MAX;
  for (int i = o0; i < o1; i++) {
    int2 p = pack[i];
    int src = p.x, eid = p.y;
    const float4* eap = (const float4*)(eattr + (size_t)eid * EDIM);
    float4 e0 = eap[0], e1 = eap[1], e2 = eap[2], e3 = eap[3];
    float xs = Xs[(size_t)src * FF + lane];
    float et = e0.x * mw[0] + e0.y * mw[1] + e0.z * mw[2] + e0.w * mw[3]
             + e1.x * mw[4] + e1.y * mw[5] + e1.z * mw[6] + e1.w * mw[7]
             + e2.x * mw[8] + e2.y * mw[9] + e2.z * mw[10] + e2.w * mw[11]
             + e3.x * mw[12] + e3.y * mw[13] + e3.z * mw[14] + e3.w * mw[15];
    float h = xd + xs + bc + et;
    s += h;
    sq += h * h;
    mn = fminf(mn, h);
    mx = fmaxf(mx, h);
  }
  float d = (float)deg[n];
  float dc = fmaxf(d, 1.0f);
  float mean = s / dc;
  float msq = sq / dc;
  float sd = sqrtf(fmaxf(msq - mean * mean, 0.0f) + 1e-5f);
  bool has = d > 0.0f;
  float vmn = has ? mn : 0.0f;
  float vmx = has ? mx : 0.0f;
  size_t b = (size_t)n * 256;
  aggs[b + lane] = mean;
  aggs[b + 64 + lane] = vmn;
  aggs[b + 128 + lane] = vmx;
  aggs[b + 192 + lane] = sd;
}

// ---------------------------------------------------------------- y = (A @ Wpost + bpost) @ Wlin + blin,  A = [x, aggs, amp*aggs, att*aggs]
__global__ __launch_bounds__(256) void k_post(const float* __restrict__ x, const float* __restrict__ aggs,
                                              const float* __restrict__ amp, const float* __restrict__ att,
                                              const float* __restrict__ Wpost, const float* __restrict__ bpost,
                                              const float* __restrict__ Wlin, const float* __restrict__ blin,
                                              float* __restrict__ y) {
  __shared__ float At[64 * 64];
  __shared__ float Ot[64 * 64];
  int t = threadIdx.x;
  int lane = t & 63;
  int wid = __builtin_amdgcn_readfirstlane(t >> 6);
  int f0 = wid * 16;
  int n0 = blockIdx.x * 64;
  int row = t >> 2;
  int c0 = (t & 3) * 4;
  bool rok = (n0 + row) < NN;
  float sc_amp = rok ? amp[n0 + row] : 0.f;
  float sc_att = rok ? att[n0 + row] : 0.f;
  float acc[16];
  #pragma unroll
  for (int j = 0; j < 16; j++) acc[j] = 0.f;

  for (int kc = 0; kc < 13; kc++) {
    const float* srcb;
    float scale = 1.0f;
    if (kc == 0) {
      srcb = x + (size_t)(n0 + row) * FF;
    } else if (kc <= 4) {
      srcb = aggs + (size_t)(n0 + row) * 256 + (kc - 1) * 64;
    } else if (kc <= 8) {
      srcb = aggs + (size_t)(n0 + row) * 256 + (kc - 5) * 64;
      scale = sc_amp;
    } else {
      srcb = aggs + (size_t)(n0 + row) * 256 + (kc - 9) * 64;
      scale = sc_att;
    }
    #pragma unroll
    for (int c4 = 0; c4 < 4; c4++) {
      int c = c0 + c4;
      float4 v = rok ? *(const float4*)(srcb + c * 4) : make_float4(0.f, 0.f, 0.f, 0.f);
      v.x *= scale; v.y *= scale; v.z *= scale; v.w *= scale;
      int cs = c ^ (row & 15);
      *(float4*)&At[row * 64 + cs * 4] = v;
    }
    __syncthreads();
    int kbase = kc * 64;
    for (int kk = 0; kk < 16; kk++) {
      int cs2 = kk ^ (lane & 15);
      float4 a4 = *(const float4*)&At[lane * 64 + cs2 * 4];
      const float* ap = (const float*)&a4;
      #pragma unroll
      for (int j4 = 0; j4 < 4; j4++) {
        int k = kbase + kk * 4 + j4;
        float av = ap[j4];
        #pragma unroll
        for (int j = 0; j < 16; j++) acc[j] += av * Wpost[(size_t)k * FF + f0 + j];
      }
    }
    __syncthreads();
  }
  #pragma unroll
  for (int j = 0; j < 16; j++) acc[j] += bpost[f0 + j];
  #pragma unroll
  for (int c4 = 0; c4 < 4; c4++) {
    int c = wid * 4 + c4;
    int cs = c ^ (lane & 15);
    float4 v = make_float4(acc[c4 * 4 + 0], acc[c4 * 4 + 1], acc[c4 * 4 + 2], acc[c4 * 4 + 3]);
    *(float4*)&Ot[lane * 64 + cs * 4] = v;
  }
  __syncthreads();
  float acc2[16];
  #pragma unroll
  for (int j = 0; j < 16; j++) acc2[j] = blin[f0 + j];
  for (int kk = 0; kk < 16; kk++) {
    int cs2 = kk ^ (lane & 15);
    float4 a4 = *(const float4*)&Ot[lane * 64 + cs2 * 4];
    const float* ap = (const float*)&a4;
    #pragma unroll
    for (int j4 = 0; j4 < 4; j4++) {
      int k = kk * 4 + j4;
      float av = ap[j4];
      #pragma unroll
      for (int j = 0; j < 16; j++) acc2[j] += av * Wlin[k * FF + f0 + j];
    }
  }
  if (n0 + lane < NN) {
    #pragma unroll
    for (int c4 = 0; c4 < 4; c4++) {
      float4 v = make_float4(acc2[c4 * 4 + 0], acc2[c4 * 4 + 1], acc2[c4 * 4 + 2], acc2[c4 * 4 + 3]);
      *(float4*)(y + (size_t)(n0 + lane) * FF + f0 + c4 * 4) = v;
    }
  }
}

// ---------------------------------------------------------------- BN stats
__global__ __launch_bounds__(256) void k_bnstats(const float* __restrict__ y, double* __restrict__ bnsum,
                                                 double* __restrict__ bnsq) {
  int f = threadIdx.x & 63;
  int rw = threadIdx.x >> 6;
  float s = 0.f, q = 0.f;
  for (int n = blockIdx.x * 4 + rw; n < NN; n += gridDim.x * 4) {
    float v = y[(size_t)n * FF + f];
    s += v;
    q += v * v;
  }
  __shared__ float ls[256], lq[256];
  ls[threadIdx.x] = s;
  lq[threadIdx.x] = q;
  __syncthreads();
  if (threadIdx.x < 64) {
    s = ls[f] + ls[f + 64] + ls[f + 128] + ls[f + 192];
    q = lq[f] + lq[f + 64] + lq[f + 128] + lq[f + 192];
    atomicAdd(&bnsum[f], (double)s);
    atomicAdd(&bnsq[f], (double)q);
  }
}

// ---------------------------------------------------------------- BN finalize: per-feature scale/offset (fused (y-mu)*sc+beta = y*sc+ofs)
__global__ void k_bnfin(const double* __restrict__ bnsum, const double* __restrict__ bnsq,
                        const float* __restrict__ gamma, const float* __restrict__ beta,
                        float* __restrict__ scb) {
  int f = threadIdx.x;  // 0..63
  double mu = bnsum[f] / (double)NN;
  double var = bnsq[f] / (double)NN - mu * mu;
  float sc = gamma[f] * rsqrtf((float)fmax(var, 0.0) + 1e-5f);
  scb[f] = sc;
  scb[64 + f] = beta[f] - (float)mu * sc;
}

// ---------------------------------------------------------------- BN apply + relu, pure elementwise float4
__global__ __launch_bounds__(256) void k_bnapply(const float* __restrict__ y, const float* __restrict__ scb,
                                                 float* __restrict__ xout) {
  int idx = blockIdx.x * 256 + threadIdx.x;  // over NN*16 float4s
  if (idx >= NN * 16) return;
  int f4 = idx & 15;
  float4 v = ((const float4*)y)[idx];
  float4 sc = ((const float4*)scb)[f4];
  float4 of = ((const float4*)(scb + 64))[f4];
  v.x = fmaxf(v.x * sc.x + of.x, 0.0f);
  v.y = fmaxf(v.y * sc.y + of.y, 0.0f);
  v.z = fmaxf(v.z * sc.z + of.z, 0.0f);
  v.w = fmaxf(v.w * sc.w + of.w, 0.0f);
  ((float4*)xout)[idx] = v;
}

// ---------------------------------------------------------------- pooling over sorted batch: running per-wave segment sum, flush at boundary
__global__ __launch_bounds__(256) void k_pool(const float* __restrict__ x, const int* __restrict__ batch,
                                              float* __restrict__ psum, float* __restrict__ cnt) {
  int lane = threadIdx.x & 63;
  int wv = threadIdx.x >> 6;
  int wglobal = blockIdx.x * 4 + wv;
  int nw = gridDim.x * 4;
  int per = (NN + nw - 1) / nw;
  int n0 = wglobal * per;
  int n1 = min(n0 + per, NN);
  if (n0 >= n1) return;
  int gcur = batch[n0];
  float acc = 0.0f;
  int count = 0;
  for (int n = n0; n < n1; n++) {
    int g = batch[n];
    float v = x[(size_t)n * FF + lane];
    if (g != gcur) {
      atomicAdd(&psum[gcur * FF + lane], acc);
      if (lane == 0) atomicAdd(&cnt[gcur], (float)count);
      gcur = g; acc = 0.0f; count = 0;
    }
    acc += v;
    count++;
  }
  atomicAdd(&psum[gcur * FF + lane], acc);
  if (lane == 0) atomicAdd(&cnt[gcur], (float)count);
}

// ---------------------------------------------------------------- final MLP over pooled means
__global__ void k_final(const float* __restrict__ psum, const float* __restrict__ cnt,
                        const float* __restrict__ W1, const float* __restrict__ b1,
                        const float* __restrict__ W2, const float* __restrict__ b2, float* __restrict__ out) {
  int g = threadIdx.x;
  if (g >= GG) return;
  float c = fmaxf(cnt[g], 1.0f);
  float gm[64];
  #pragma unroll
  for (int i = 0; i < 64; i++) gm[i] = psum[g * FF + i] / c;
  float o = b2[0];
  for (int h = 0; h < 40; h++) {
    float a = b1[h];
    #pragma unroll
    for (int i = 0; i < 64; i++) a += gm[i] * W1[i * 40 + h];
    o += fmaxf(a, 0.0f) * W2[h];
  }
  out[g] = o;
}

// ================================================================ launch
extern "C" void kernel_launch(void* const* d_in, const int* in_sizes, int n_in,
                              void* d_out, int out_size, void* d_ws, size_t ws_size,
                              hipStream_t stream) {
  (void)in_sizes; (void)n_in; (void)out_size; (void)ws_size;
  const float* x0    = (const float*)d_in[0];
  const float* eattr = (const float*)d_in[1];
  const float* We    = (const float*)d_in[2];
  const float* be    = (const float*)d_in[3];
  const float* Wpre  = (const float*)d_in[4];
  const float* bpre  = (const float*)d_in[5];
  const float* Wpost = (const float*)d_in[6];
  const float* bpost = (const float*)d_in[7];
  const float* Wlin  = (const float*)d_in[8];
  const float* blin  = (const float*)d_in[9];
  const float* gamma = (const float*)d_in[10];
  const float* beta  = (const float*)d_in[11];
  const float* W1    = (const float*)d_in[12];
  const float* b1    = (const float*)d_in[13];
  const float* W2    = (const float*)d_in[14];
  const float* b2    = (const float*)d_in[15];
  const int* eidx    = (const int*)d_in[16];
  const int* batch   = (const int*)d_in[17];
  float* out = (float*)d_out;

  char* w = (char*)d_ws;
  size_t off = 0;
  auto alloc = [&](size_t bytes) -> void* {
    void* p = w + off;
    off += bytes;
    off = (off + 255) & ~(size_t)255;
    return p;
  };
  int*    deg     = (int*)alloc(NN * sizeof(int));
  int*    offsets = (int*)alloc((NN + 1) * sizeof(int));
  int*    cursor  = (int*)alloc(NN * sizeof(int));
  int2*   pack    = (int2*)alloc(EE * sizeof(int2));
  double* avgacc  = (double*)alloc(sizeof(double));
  double* bnsum   = (double*)alloc(FF * sizeof(double));
  double* bnsq    = (double*)alloc(FF * sizeof(double));
  float*  amp     = (float*)alloc(NN * sizeof(float));
  float*  att     = (float*)alloc(NN * sizeof(float));
  float*  Mw      = (float*)alloc(EDIM * FF * sizeof(float));
  float*  bconst  = (float*)alloc(FF * sizeof(float));
  float*  scb     = (float*)alloc(2 * FF * sizeof(float));
  float*  Xd      = (float*)alloc((size_t)NN * FF * sizeof(float));
  float*  Xs      = (float*)alloc((size_t)NN * FF * sizeof(float));
  float*  aggs    = (float*)alloc((size_t)NN * 256 * sizeof(float));
  float*  ybuf    = (float*)alloc((size_t)NN * FF * sizeof(float));
  float*  xcur    = (float*)alloc((size_t)NN * FF * sizeof(float));
  float*  psum    = (float*)alloc((GG * FF + GG) * sizeof(float));
  float*  cnt     = psum + GG * FF;

  hipMemsetAsync(deg, 0, NN * sizeof(int), stream);
  hipMemsetAsync(cursor, 0, NN * sizeof(int), stream);
  hipMemsetAsync(avgacc, 0, sizeof(double), stream);
  hipMemsetAsync(psum, 0, (GG * FF + GG) * sizeof(float), stream);

  k_deg<<<(EE + 255) / 256, 256, 0, stream>>>(eidx, deg);
  k_avglog<<<(NN + 255) / 256, 256, 0, stream>>>(deg, avgacc);
  k_scan<<<1, 1024, 0, stream>>>(deg, offsets);
  k_scatter<<<(EE + 255) / 256, 256, 0, stream>>>(eidx, offsets, cursor, pack);
  k_ampatt<<<(NN + 255) / 256, 256, 0, stream>>>(deg, avgacc, amp, att);

  const float* xin = x0;
  const int nb64 = (NN + 63) / 64;  // 782
  for (int l = 0; l < 2; l++) {
    k_prep<<<1, 64, 0, stream>>>(We + l * EDIM * FF, be + l * FF, Wpre + l * 3 * FF * FF,
                                 bpre + l * FF, Mw, bconst, bnsum, bnsq);
    k_xform<<<nb64, 256, 0, stream>>>(xin, Wpre + l * 3 * FF * FF, Xd, Xs);
    k_agg<<<(NN + 3) / 4, 256, 0, stream>>>(pack, offsets, deg, eattr, Mw, bconst, Xd, Xs, aggs);
    k_post<<<nb64, 256, 0, stream>>>(xin, aggs, amp, att, Wpost + (size_t)l * 832 * FF,
                                     bpost + l * FF, Wlin + l * FF * FF, blin + l * FF, ybuf);
    k_bnstats<<<256, 256, 0, stream>>>(ybuf, bnsum, bnsq);
    k_bnfin<<<1, 64, 0, stream>>>(bnsum, bnsq, gamma + l * FF, beta + l * FF, scb);
    k_bnapply<<<(NN * 16 + 255) / 256, 256, 0, stream>>>(ybuf, scb, xcur);
    xin = xcur;
  }
  k_pool<<<200, 256, 0, stream>>>(xcur, batch, psum, cnt);
  k_final<<<1, 64, 0, stream>>>(psum, cnt, W1, b1, W2, b2, out);
}

// Round 4
// 670.775 us; speedup vs baseline: 1.9341x; 1.3256x over previous
//
#include <hip/hip_runtime.h>
#include <math.h>
#include <float.h>

#define NN 50000
#define EE 800000
#define FF 64
#define EDIM 16
#define GG 64
#define NB64 782   // ceil(NN/64)

typedef short bf16x8 __attribute__((ext_vector_type(8)));
typedef float f32x4 __attribute__((ext_vector_type(4)));

__device__ inline unsigned short bf_rne(float v) {
  unsigned int u = __float_as_uint(v);
  unsigned int r = (u + 0x7FFFu + ((u >> 16) & 1u)) >> 16;
  return (unsigned short)r;
}
__device__ inline float bf_up(unsigned short h) {
  return __uint_as_float(((unsigned int)h) << 16);
}
__device__ inline void split4(float4 v, ushort4& h, ushort4& l) {
  h.x = bf_rne(v.x); h.y = bf_rne(v.y); h.z = bf_rne(v.z); h.w = bf_rne(v.w);
  l.x = bf_rne(v.x - bf_up(h.x));
  l.y = bf_rne(v.y - bf_up(h.y));
  l.z = bf_rne(v.z - bf_up(h.z));
  l.w = bf_rne(v.w - bf_up(h.w));
}

// ---------------------------------------------------------------- degree
__global__ void k_deg(const int* __restrict__ eidx, int* __restrict__ deg) {
  int e = blockIdx.x * 256 + threadIdx.x;
  if (e < EE) atomicAdd(&deg[eidx[EE + e]], 1);
}

// ---------------------------------------------------------------- avg log(deg+1)
__global__ void k_avglog(const int* __restrict__ deg, double* __restrict__ acc) {
  int n = blockIdx.x * 256 + threadIdx.x;
  float v = (n < NN) ? logf((float)deg[n] + 1.0f) : 0.0f;
  __shared__ float s[256];
  s[threadIdx.x] = v;
  __syncthreads();
  for (int o = 128; o > 0; o >>= 1) {
    if (threadIdx.x < o) s[threadIdx.x] += s[threadIdx.x + o];
    __syncthreads();
  }
  if (threadIdx.x == 0) atomicAdd(acc, (double)s[0]);
}

// ---------------------------------------------------------------- exclusive scan of deg -> offsets (single block)
__global__ __launch_bounds__(1024) void k_scan(const int* __restrict__ deg, int* __restrict__ offsets) {
  __shared__ int wsum[16];
  __shared__ int s_carry;
  int t = threadIdx.x;
  int lane = t & 63;
  int wid = t >> 6;
  if (t == 0) s_carry = 0;
  __syncthreads();
  for (int base = 0; base < NN; base += 1024) {
    int idx = base + t;
    int v = (idx < NN) ? deg[idx] : 0;
    int x = v;
    #pragma unroll
    for (int o = 1; o < 64; o <<= 1) {
      int y = __shfl_up(x, o);
      if (lane >= o) x += y;
    }
    if (lane == 63) wsum[wid] = x;
    __syncthreads();
    if (wid == 0 && lane < 16) {
      int wv = wsum[lane];
      #pragma unroll
      for (int o = 1; o < 16; o <<= 1) {
        int y = __shfl_up(wv, o);
        if (lane >= o) wv += y;
      }
      wsum[lane] = wv;
    }
    __syncthreads();
    int pre = (wid > 0 ? wsum[wid - 1] : 0) + s_carry;
    if (idx < NN) offsets[idx] = pre + x - v;  // exclusive
    __syncthreads();
    if (t == 0) s_carry += wsum[15];
    __syncthreads();
  }
  if (threadIdx.x == 0) offsets[NN] = s_carry;
}

// ---------------------------------------------------------------- scatter edges into CSR slots
__global__ void k_scatter(const int* __restrict__ eidx, const int* __restrict__ offsets,
                          int* __restrict__ cursor, int2* __restrict__ pack) {
  int e = blockIdx.x * 256 + threadIdx.x;
  if (e < EE) {
    int s = eidx[e];
    int d = eidx[EE + e];
    int pos = offsets[d] + atomicAdd(&cursor[d], 1);
    pack[pos] = make_int2(s, e);
  }
}

// ---------------------------------------------------------------- amp/att
__global__ void k_ampatt(const int* __restrict__ deg, const double* __restrict__ acc,
                         float* __restrict__ amp, float* __restrict__ att) {
  int n = blockIdx.x * 256 + threadIdx.x;
  if (n < NN) {
    float avg = (float)(acc[0] / (double)NN);
    float d = (float)deg[n];
    float logd = logf(fmaxf(d, 1.0f) + 1.0f);
    amp[n] = logd / avg;
    att[n] = avg / logd;
  }
}

// ---------------------------------------------------------------- per-layer prep
__global__ __launch_bounds__(256) void k_prep2(const float* __restrict__ We, const float* __restrict__ be,
                                               const float* __restrict__ Wpre, const float* __restrict__ bpre,
                                               const float* __restrict__ Wpost, const float* __restrict__ bpost,
                                               const float* __restrict__ Wlin, const float* __restrict__ blin,
                                               float* __restrict__ Mw, float* __restrict__ bconst,
                                               unsigned short* __restrict__ WcT_h, unsigned short* __restrict__ WcT_l,
                                               unsigned short* __restrict__ WxT_h, unsigned short* __restrict__ WxT_l,
                                               float* __restrict__ bcomb) {
  int id = blockIdx.x * 256 + threadIdx.x;
  if (id < 53248) {                      // WcombT
    int k = id >> 6, f = id & 63;
    float a = 0.0f;
    for (int j = 0; j < FF; j++) a += Wpost[(size_t)k * FF + j] * Wlin[j * FF + f];
    unsigned short h = bf_rne(a);
    WcT_h[f * 832 + k] = h;
    WcT_l[f * 832 + k] = bf_rne(a - bf_up(h));
  } else if (id < 61440) {               // WxT
    int lid = id - 53248;
    int j = lid >> 6, k = lid & 63;
    float v = (j < 64) ? Wpre[k * FF + j] : Wpre[(64 + k) * FF + (j - 64)];
    unsigned short h = bf_rne(v);
    WxT_h[j * 64 + k] = h;
    WxT_l[j * 64 + k] = bf_rne(v - bf_up(h));
  } else if (id < 62464) {               // Mw
    int lid = id - 61440;
    int k = lid >> 6, f = lid & 63;
    float a = 0.0f;
    for (int j = 0; j < FF; j++) a += We[k * FF + j] * Wpre[(128 + j) * FF + f];
    Mw[k * FF + f] = a;
  } else {                               // biases
    int f = threadIdx.x;
    if (blockIdx.x == 244 && f < 64) {
      float b = bpre[f];
      for (int j = 0; j < FF; j++) b += be[j] * Wpre[(128 + j) * FF + f];
      bconst[f] = b;
      float c = blin[f];
      for (int j = 0; j < FF; j++) c += bpost[j] * Wlin[j * FF + f];
      bcomb[f] = c;
    }
  }
}

// ---------------------------------------------------------------- [Xd|Xs] = x @ Wx  via bf16x3 MFMA
__global__ __launch_bounds__(256) void k_xform(const float* __restrict__ x,
                                               const unsigned short* __restrict__ WxT_h,
                                               const unsigned short* __restrict__ WxT_l,
                                               float* __restrict__ Xd, float* __restrict__ Xs) {
  __shared__ unsigned short Ah[64 * 72], Al[64 * 72];
  __shared__ unsigned short Bh[128 * 72], Bl[128 * 72];
  int t = threadIdx.x;
  int n0 = blockIdx.x * 64;
  // stage B (weights, [col][k] layout, row stride 72); each thread: 32 k-elems
  {
    int j = t >> 1, half = t & 1;
    const ushort4* srch = (const ushort4*)(WxT_h + j * 64 + half * 32);
    const ushort4* srcl = (const ushort4*)(WxT_l + j * 64 + half * 32);
    #pragma unroll
    for (int i = 0; i < 8; i++) {
      *(ushort4*)&Bh[j * 72 + half * 32 + i * 4] = srch[i];
      *(ushort4*)&Bl[j * 72 + half * 32 + i * 4] = srcl[i];
    }
  }
  // stage A (x rows, f32 -> hi/lo bf16)
  {
    int r = t >> 2, c0 = (t & 3) * 16;
    int n = n0 + r;
    bool rok = n < NN;
    const float4* src = (const float4*)(x + (size_t)n * FF + c0);
    #pragma unroll
    for (int c4 = 0; c4 < 4; c4++) {
      float4 v = rok ? src[c4] : make_float4(0.f, 0.f, 0.f, 0.f);
      ushort4 h4, l4;
      split4(v, h4, l4);
      *(ushort4*)&Ah[r * 72 + c0 + c4 * 4] = h4;
      *(ushort4*)&Al[r * 72 + c0 + c4 * 4] = l4;
    }
  }
  __syncthreads();
  int lane = t & 63;
  int l15 = lane & 15;
  int quad = lane >> 4;
  int w = __builtin_amdgcn_readfirstlane(t >> 6);
  int rbase = (w & 1) * 32;
  int cbase = (w >> 1) * 64;
  f32x4 acc[2][4];
  #pragma unroll
  for (int rt = 0; rt < 2; rt++)
    #pragma unroll
    for (int ct = 0; ct < 4; ct++) acc[rt][ct] = (f32x4){0.f, 0.f, 0.f, 0.f};

  #pragma unroll
  for (int ks = 0; ks < 2; ks++) {
    bf16x8 a_h[2], a_l[2];
    #pragma unroll
    for (int rt = 0; rt < 2; rt++) {
      int row = rbase + rt * 16 + l15;
      a_h[rt] = *(const bf16x8*)&Ah[row * 72 + ks * 32 + quad * 8];
      a_l[rt] = *(const bf16x8*)&Al[row * 72 + ks * 32 + quad * 8];
    }
    #pragma unroll
    for (int ct = 0; ct < 4; ct++) {
      int col = cbase + ct * 16 + l15;
      bf16x8 b_h = *(const bf16x8*)&Bh[col * 72 + ks * 32 + quad * 8];
      bf16x8 b_l = *(const bf16x8*)&Bl[col * 72 + ks * 32 + quad * 8];
      #pragma unroll
      for (int rt = 0; rt < 2; rt++) {
        acc[rt][ct] = __builtin_amdgcn_mfma_f32_16x16x32_bf16(a_h[rt], b_h, acc[rt][ct], 0, 0, 0);
        acc[rt][ct] = __builtin_amdgcn_mfma_f32_16x16x32_bf16(a_h[rt], b_l, acc[rt][ct], 0, 0, 0);
        acc[rt][ct] = __builtin_amdgcn_mfma_f32_16x16x32_bf16(a_l[rt], b_h, acc[rt][ct], 0, 0, 0);
      }
    }
  }
  // store: cols 0..63 -> Xd, 64..127 -> Xs
  #pragma unroll
  for (int rt = 0; rt < 2; rt++) {
    #pragma unroll
    for (int ct = 0; ct < 4; ct++) {
      int col = cbase + ct * 16 + l15;
      float* dst = (col < 64) ? (Xd + col) : (Xs + col - 64);
      #pragma unroll
      for (int reg = 0; reg < 4; reg++) {
        int n = n0 + rbase + rt * 16 + quad * 4 + reg;
        if (n < NN) dst[(size_t)n * FF] = acc[rt][ct][reg];
      }
    }
  }
}

// ---------------------------------------------------------------- per-node CSR aggregation -> aggs [N,256]
__global__ __launch_bounds__(256) void k_agg(const int2* __restrict__ pack, const int* __restrict__ offsets,
                                             const int* __restrict__ deg, const float* __restrict__ eattr,
                                             const float* __restrict__ Mw, const float* __restrict__ bconst,
                                             const float* __restrict__ Xd, const float* __restrict__ Xs,
                                             float* __restrict__ aggs) {
  int wid = __builtin_amdgcn_readfirstlane(threadIdx.x >> 6);
  int lane = threadIdx.x & 63;
  int n = blockIdx.x * 4 + wid;
  if (n >= NN) return;
  float mw[16];
  #pragma unroll
  for (int k = 0; k < 16; k++) mw[k] = Mw[k * FF + lane];
  float bc = bconst[lane];
  float xd = Xd[(size_t)n * FF + lane];
  int o0 = offsets[n], o1 = offsets[n + 1];
  float s = 0.f, sq = 0.f, mn = FLT_MAX, mx = -FLT_MAX;
  for (int i = o0; i < o1; i++) {
    int2 p = pack[i];
    int src = p.x, eid = p.y;
    const float4* eap = (const float4*)(eattr + (size_t)eid * EDIM);
    float4 e0 = eap[0], e1 = eap[1], e2 = eap[2], e3 = eap[3];
    float xs = Xs[(size_t)src * FF + lane];
    float et = e0.x * mw[0] + e0.y * mw[1] + e0.z * mw[2] + e0.w * mw[3]
             + e1.x * mw[4] + e1.y * mw[5] + e1.z * mw[6] + e1.w * mw[7]
             + e2.x * mw[8] + e2.y * mw[9] + e2.z * mw[10] + e2.w * mw[11]
             + e3.x * mw[12] + e3.y * mw[13] + e3.z * mw[14] + e3.w * mw[15];
    float h = xd + xs + bc + et;
    s += h;
    sq += h * h;
    mn = fminf(mn, h);
    mx = fmaxf(mx, h);
  }
  float d = (float)deg[n];
  float dc = fmaxf(d, 1.0f);
  float mean = s / dc;
  float msq = sq / dc;
  float sd = sqrtf(fmaxf(msq - mean * mean, 0.0f) + 1e-5f);
  bool has = d > 0.0f;
  float vmn = has ? mn : 0.0f;
  float vmx = has ? mx : 0.0f;
  size_t b = (size_t)n * 256;
  aggs[b + lane] = mean;
  aggs[b + 64 + lane] = vmn;
  aggs[b + 128 + lane] = vmx;
  aggs[b + 192 + lane] = sd;
}

// ---------------------------------------------------------------- y = A @ Wcomb + bcomb  (bf16x3 MFMA) + BN partials
__global__ __launch_bounds__(256) void k_post(const float* __restrict__ x, const float* __restrict__ aggs,
                                              const float* __restrict__ amp, const float* __restrict__ att,
                                              const unsigned short* __restrict__ WcT_h,
                                              const unsigned short* __restrict__ WcT_l,
                                              const float* __restrict__ bcomb,
                                              float* __restrict__ y, float* __restrict__ partials) {
  __shared__ unsigned short Ah[64 * 72], Al[64 * 72];
  __shared__ unsigned short Bh[64 * 72], Bl[64 * 72];
  __shared__ float red_s[4][32], red_q[4][32];
  int t = threadIdx.x;
  int n0 = blockIdx.x * 64;
  int lane = t & 63;
  int l15 = lane & 15;
  int quad = lane >> 4;
  int w = __builtin_amdgcn_readfirstlane(t >> 6);
  int rbase = (w & 1) * 32;
  int cbase = (w >> 1) * 32;

  int ar = t >> 2;                // staging row (A) / col (B)
  int ac0 = (t & 3) * 16;
  int an = n0 + ar;
  bool rok = an < NN;
  float sc_amp = rok ? amp[an] : 0.f;
  float sc_att = rok ? att[an] : 0.f;
  const float* xrow = x + (size_t)an * FF;
  const float* arow = aggs + (size_t)an * 256;

  f32x4 acc[2][2];
  #pragma unroll
  for (int rt = 0; rt < 2; rt++)
    #pragma unroll
    for (int ct = 0; ct < 2; ct++) acc[rt][ct] = (f32x4){0.f, 0.f, 0.f, 0.f};

  for (int kc = 0; kc < 13; kc++) {
    // ---- stage A chunk [64 rows][64 k]
    const float* srcb;
    float scale = 1.0f;
    if (kc == 0) {
      srcb = xrow;
    } else {
      int kcm = kc - 1;
      srcb = arow + (kcm & 3) * 64;
      int sel = kcm >> 2;
      scale = (sel == 0) ? 1.0f : (sel == 1 ? sc_amp : sc_att);
    }
    #pragma unroll
    for (int c4 = 0; c4 < 4; c4++) {
      float4 v = rok ? *(const float4*)(srcb + ac0 + c4 * 4) : make_float4(0.f, 0.f, 0.f, 0.f);
      v.x *= scale; v.y *= scale; v.z *= scale; v.w *= scale;
      ushort4 h4, l4;
      split4(v, h4, l4);
      *(ushort4*)&Ah[ar * 72 + ac0 + c4 * 4] = h4;
      *(ushort4*)&Al[ar * 72 + ac0 + c4 * 4] = l4;
    }
    // ---- stage B chunk [64 cols][64 k]; each thread: 16 k-elems
    {
      int kbase = kc * 64;
      const ushort4* sh = (const ushort4*)(WcT_h + ar * 832 + kbase + ac0);
      const ushort4* sl = (const ushort4*)(WcT_l + ar * 832 + kbase + ac0);
      #pragma unroll
      for (int i = 0; i < 4; i++) {
        *(ushort4*)&Bh[ar * 72 + ac0 + i * 4] = sh[i];
        *(ushort4*)&Bl[ar * 72 + ac0 + i * 4] = sl[i];
      }
    }
    __syncthreads();
    #pragma unroll
    for (int ks = 0; ks < 2; ks++) {
      bf16x8 a_h[2], a_l[2], b_h[2], b_l[2];
      #pragma unroll
      for (int rt = 0; rt < 2; rt++) {
        int row = rbase + rt * 16 + l15;
        a_h[rt] = *(const bf16x8*)&Ah[row * 72 + ks * 32 + quad * 8];
        a_l[rt] = *(const bf16x8*)&Al[row * 72 + ks * 32 + quad * 8];
      }
      #pragma unroll
      for (int ct = 0; ct < 2; ct++) {
        int col = cbase + ct * 16 + l15;
        b_h[ct] = *(const bf16x8*)&Bh[col * 72 + ks * 32 + quad * 8];
        b_l[ct] = *(const bf16x8*)&Bl[col * 72 + ks * 32 + quad * 8];
      }
      #pragma unroll
      for (int rt = 0; rt < 2; rt++)
        #pragma unroll
        for (int ct = 0; ct < 2; ct++) {
          acc[rt][ct] = __builtin_amdgcn_mfma_f32_16x16x32_bf16(a_h[rt], b_h[ct], acc[rt][ct], 0, 0, 0);
          acc[rt][ct] = __builtin_amdgcn_mfma_f32_16x16x32_bf16(a_h[rt], b_l[ct], acc[rt][ct], 0, 0, 0);
          acc[rt][ct] = __builtin_amdgcn_mfma_f32_16x16x32_bf16(a_l[rt], b_h[ct], acc[rt][ct], 0, 0, 0);
        }
    }
    __syncthreads();
  }

  // ---- epilogue: bias, store y, BN partials
  float ps[2] = {0.f, 0.f}, pq[2] = {0.f, 0.f};
  #pragma unroll
  for (int ct = 0; ct < 2; ct++) {
    int col = cbase + ct * 16 + l15;
    float bc = bcomb[col];
    #pragma unroll
    for (int rt = 0; rt < 2; rt++) {
      #pragma unroll
      for (int reg = 0; reg < 4; reg++) {
        int n = n0 + rbase + rt * 16 + quad * 4 + reg;
        float v = acc[rt][ct][reg] + bc;
        if (n < NN) {
          y[(size_t)n * FF + col] = v;
          ps[ct] += v;
          pq[ct] += v * v;
        }
      }
    }
  }
  #pragma unroll
  for (int ct = 0; ct < 2; ct++) {
    ps[ct] += __shfl_xor(ps[ct], 16);
    ps[ct] += __shfl_xor(ps[ct], 32);
    pq[ct] += __shfl_xor(pq[ct], 16);
    pq[ct] += __shfl_xor(pq[ct], 32);
  }
  if (quad == 0) {
    #pragma unroll
    for (int ct = 0; ct < 2; ct++) {
      red_s[w][ct * 16 + l15] = ps[ct];
      red_q[w][ct * 16 + l15] = pq[ct];
    }
  }
  __syncthreads();
  if (t < 64) {
    float ss, qq;
    if (t < 32) { ss = red_s[0][t] + red_s[1][t]; qq = red_q[0][t] + red_q[1][t]; }
    else        { ss = red_s[2][t - 32] + red_s[3][t - 32]; qq = red_q[2][t - 32] + red_q[3][t - 32]; }
    partials[(size_t)blockIdx.x * 128 + t] = ss;
    partials[(size_t)blockIdx.x * 128 + 64 + t] = qq;
  }
}

// ---------------------------------------------------------------- reduce BN partials -> scb (scale, offset)
__global__ __launch_bounds__(1024) void k_bnfin(const float* __restrict__ partials,
                                                const float* __restrict__ gamma, const float* __restrict__ beta,
                                                float* __restrict__ scb) {
  __shared__ float red[1024];
  __shared__ double tot[128];
  int t = threadIdx.x;
  int c = t & 127, seg = t >> 7;
  float s = 0.f;
  for (int i = seg; i < NB64; i += 8) s += partials[(size_t)i * 128 + c];
  red[t] = s;
  __syncthreads();
  if (t < 128) {
    double d = 0.0;
    #pragma unroll
    for (int sg = 0; sg < 8; sg++) d += (double)red[sg * 128 + t];
    tot[t] = d;
  }
  __syncthreads();
  if (t < 64) {
    double mu = tot[t] / (double)NN;
    double var = tot[64 + t] / (double)NN - mu * mu;
    float sc = gamma[t] * rsqrtf((float)fmax(var, 0.0) + 1e-5f);
    scb[t] = sc;
    scb[64 + t] = beta[t] - (float)mu * sc;
  }
}

// ---------------------------------------------------------------- BN apply + relu, elementwise float4
__global__ __launch_bounds__(256) void k_bnapply(const float* __restrict__ y, const float* __restrict__ scb,
                                                 float* __restrict__ xout) {
  int idx = blockIdx.x * 256 + threadIdx.x;  // over NN*16 float4s
  if (idx >= NN * 16) return;
  int f4 = idx & 15;
  float4 v = ((const float4*)y)[idx];
  float4 sc = ((const float4*)scb)[f4];
  float4 of = ((const float4*)(scb + 64))[f4];
  v.x = fmaxf(v.x * sc.x + of.x, 0.0f);
  v.y = fmaxf(v.y * sc.y + of.y, 0.0f);
  v.z = fmaxf(v.z * sc.z + of.z, 0.0f);
  v.w = fmaxf(v.w * sc.w + of.w, 0.0f);
  ((float4*)xout)[idx] = v;
}

// ---------------------------------------------------------------- pooling over sorted batch
__global__ __launch_bounds__(256) void k_pool(const float* __restrict__ x, const int* __restrict__ batch,
                                              float* __restrict__ psum, float* __restrict__ cnt) {
  int lane = threadIdx.x & 63;
  int wv = threadIdx.x >> 6;
  int wglobal = blockIdx.x * 4 + wv;
  int nw = gridDim.x * 4;
  int per = (NN + nw - 1) / nw;
  int n0 = wglobal * per;
  int n1 = min(n0 + per, NN);
  if (n0 >= n1) return;
  int gcur = batch[n0];
  float acc = 0.0f;
  int count = 0;
  for (int n = n0; n < n1; n++) {
    int g = batch[n];
    float v = x[(size_t)n * FF + lane];
    if (g != gcur) {
      atomicAdd(&psum[gcur * FF + lane], acc);
      if (lane == 0) atomicAdd(&cnt[gcur], (float)count);
      gcur = g; acc = 0.0f; count = 0;
    }
    acc += v;
    count++;
  }
  atomicAdd(&psum[gcur * FF + lane], acc);
  if (lane == 0) atomicAdd(&cnt[gcur], (float)count);
}

// ---------------------------------------------------------------- final MLP over pooled means
__global__ void k_final(const float* __restrict__ psum, const float* __restrict__ cnt,
                        const float* __restrict__ W1, const float* __restrict__ b1,
                        const float* __restrict__ W2, const float* __restrict__ b2, float* __restrict__ out) {
  int g = threadIdx.x;
  if (g >= GG) return;
  float c = fmaxf(cnt[g], 1.0f);
  float gm[64];
  #pragma unroll
  for (int i = 0; i < 64; i++) gm[i] = psum[g * FF + i] / c;
  float o = b2[0];
  for (int h = 0; h < 40; h++) {
    float a = b1[h];
    #pragma unroll
    for (int i = 0; i < 64; i++) a += gm[i] * W1[i * 40 + h];
    o += fmaxf(a, 0.0f) * W2[h];
  }
  out[g] = o;
}

// ================================================================ launch
extern "C" void kernel_launch(void* const* d_in, const int* in_sizes, int n_in,
                              void* d_out, int out_size, void* d_ws, size_t ws_size,
                              hipStream_t stream) {
  (void)in_sizes; (void)n_in; (void)out_size; (void)ws_size;
  const float* x0    = (const float*)d_in[0];
  const float* eattr = (const float*)d_in[1];
  const float* We    = (const float*)d_in[2];
  const float* be    = (const float*)d_in[3];
  const float* Wpre  = (const float*)d_in[4];
  const float* bpre  = (const float*)d_in[5];
  const float* Wpost = (const float*)d_in[6];
  const float* bpost = (const float*)d_in[7];
  const float* Wlin  = (const float*)d_in[8];
  const float* blin  = (const float*)d_in[9];
  const float* gamma = (const float*)d_in[10];
  const float* beta  = (const float*)d_in[11];
  const float* W1    = (const float*)d_in[12];
  const float* b1    = (const float*)d_in[13];
  const float* W2    = (const float*)d_in[14];
  const float* b2    = (const float*)d_in[15];
  const int* eidx    = (const int*)d_in[16];
  const int* batch   = (const int*)d_in[17];
  float* out = (float*)d_out;

  char* w = (char*)d_ws;
  size_t off = 0;
  auto alloc = [&](size_t bytes) -> void* {
    void* p = w + off;
    off += bytes;
    off = (off + 255) & ~(size_t)255;
    return p;
  };
  int*    deg     = (int*)alloc(NN * sizeof(int));
  int*    offsets = (int*)alloc((NN + 1) * sizeof(int));
  int*    cursor  = (int*)alloc(NN * sizeof(int));
  int2*   pack    = (int2*)alloc(EE * sizeof(int2));
  double* avgacc  = (double*)alloc(sizeof(double));
  float*  amp     = (float*)alloc(NN * sizeof(float));
  float*  att     = (float*)alloc(NN * sizeof(float));
  float*  Mw      = (float*)alloc(EDIM * FF * sizeof(float));
  float*  bconst  = (float*)alloc(FF * sizeof(float));
  float*  bcomb   = (float*)alloc(FF * sizeof(float));
  float*  scb     = (float*)alloc(2 * FF * sizeof(float));
  unsigned short* WcT_h = (unsigned short*)alloc(FF * 832 * sizeof(unsigned short));
  unsigned short* WcT_l = (unsigned short*)alloc(FF * 832 * sizeof(unsigned short));
  unsigned short* WxT_h = (unsigned short*)alloc(128 * 64 * sizeof(unsigned short));
  unsigned short* WxT_l = (unsigned short*)alloc(128 * 64 * sizeof(unsigned short));
  float*  partials = (float*)alloc((size_t)NB64 * 128 * sizeof(float));
  float*  Xd      = (float*)alloc((size_t)NN * FF * sizeof(float));
  float*  Xs      = (float*)alloc((size_t)NN * FF * sizeof(float));
  float*  aggs    = (float*)alloc((size_t)NN * 256 * sizeof(float));
  float*  ybuf    = (float*)alloc((size_t)NN * FF * sizeof(float));
  float*  xcur    = (float*)alloc((size_t)NN * FF * sizeof(float));
  float*  psum    = (float*)alloc((GG * FF + GG) * sizeof(float));
  float*  cnt     = psum + GG * FF;

  hipMemsetAsync(deg, 0, NN * sizeof(int), stream);
  hipMemsetAsync(cursor, 0, NN * sizeof(int), stream);
  hipMemsetAsync(avgacc, 0, sizeof(double), stream);
  hipMemsetAsync(psum, 0, (GG * FF + GG) * sizeof(float), stream);

  k_deg<<<(EE + 255) / 256, 256, 0, stream>>>(eidx, deg);
  k_avglog<<<(NN + 255) / 256, 256, 0, stream>>>(deg, avgacc);
  k_scan<<<1, 1024, 0, stream>>>(deg, offsets);
  k_scatter<<<(EE + 255) / 256, 256, 0, stream>>>(eidx, offsets, cursor, pack);
  k_ampatt<<<(NN + 255) / 256, 256, 0, stream>>>(deg, avgacc, amp, att);

  const float* xin = x0;
  for (int l = 0; l < 2; l++) {
    k_prep2<<<245, 256, 0, stream>>>(We + l * EDIM * FF, be + l * FF, Wpre + (size_t)l * 3 * FF * FF,
                                     bpre + l * FF, Wpost + (size_t)l * 832 * FF, bpost + l * FF,
                                     Wlin + l * FF * FF, blin + l * FF,
                                     Mw, bconst, WcT_h, WcT_l, WxT_h, WxT_l, bcomb);
    k_xform<<<NB64, 256, 0, stream>>>(xin, WxT_h, WxT_l, Xd, Xs);
    k_agg<<<(NN + 3) / 4, 256, 0, stream>>>(pack, offsets, deg, eattr, Mw, bconst, Xd, Xs, aggs);
    k_post<<<NB64, 256, 0, stream>>>(xin, aggs, amp, att, WcT_h, WcT_l, bcomb, ybuf, partials);
    k_bnfin<<<1, 1024, 0, stream>>>(partials, gamma + l * FF, beta + l * FF, scb);
    k_bnapply<<<(NN * 16 + 255) / 256, 256, 0, stream>>>(ybuf, scb, xcur);
    xin = xcur;
  }
  k_pool<<<200, 256, 0, stream>>>(xcur, batch, psum, cnt);
  k_final<<<1, 64, 0, stream>>>(psum, cnt, W1, b1, W2, b2, out);
}